// Round 2
// baseline (80.921 us; speedup 1.0000x reference)
//
#include <hip/hip_runtime.h>
#include <math.h>

#define EPS2f 0.25f
#define EPS4f 0.0625f

// readlane with compile-time lane: wave-uniform broadcast from a register,
// result lands in an SGPR (free operand on the consuming v_fma).
__device__ __forceinline__ float rl(float v, int l) {
    return __int_as_float(__builtin_amdgcn_readlane(__float_as_int(v), l));
}

// ---------------------------------------------------------------------------
// Kernel 1: precompute per-(ij,k) tables (unchanged from R1).
//   AB4 (float4 view)[k2*1024 + ij] = { A(2k2), B2(2k2), A(2k2+1), B2(2k2+1) }
//        A = 1/Sigma, B2 = 2*mu_t/Sigma
//   KV4 (float4 view)[ij2*64 + k]   = { K(ij_e), Vm(ij_e), K(ij_o), Vm(ij_o) }
//   C0 [ij] = sum_k ( mu_t^2/Sigma + log(Sigma) )
// ---------------------------------------------------------------------------
__global__ __launch_bounds__(256) void precomp_kernel(
    const float* __restrict__ Mu0, const float* __restrict__ Mu1,
    const float* __restrict__ S0,  const float* __restrict__ S1,
    const float* __restrict__ tptr,
    float2* __restrict__ AB2, float2* __restrict__ KV2,
    float* __restrict__ C0)
{
    __shared__ float2 abS[4][67];
    __shared__ float2 kvS[4][64];

    const int tid = threadIdx.x;
    const int k   = tid & 63;
    const int ijl = tid >> 6;
    const int ij0 = blockIdx.x << 2;
    const int ij  = ij0 + ijl;
    const int i   = ij >> 5;
    const int j   = ij & 31;
    const float t   = *tptr;
    const float omt = 1.0f - t;

    const float s0 = S0[i * 64 + k];
    const float s1 = S1[j * 64 + k];
    const float m0 = Mu0[i * 64 + k];
    const float m1 = Mu1[j * 64 + k];

    const float ds  = sqrtf(4.0f * s0 * s1 + EPS4f);
    const float cs  = 0.5f * (ds - EPS2f);
    const float mt  = omt * m0 + t * m1;
    const float sig = omt * omt * s0 + t * t * s1
                    + 2.0f * t * omt * (cs + 0.5f * EPS2f);
    const float isig = 1.0f / sig;
    const float st = t * s1 - omt * s0 + (omt - t) * cs - EPS2f * t;
    const float kk = st * isig;
    const float v  = m1 - m0;

    abS[ijl][k] = make_float2(isig, 2.0f * mt * isig);
    kvS[ijl][k] = make_float2(kk, v - kk * mt);

    float c = mt * mt * isig + __logf(sig);
    #pragma unroll
    for (int off = 32; off >= 1; off >>= 1)
        c += __shfl_xor(c, off, 64);
    if (k == 0) C0[ij] = c;

    __syncthreads();

    {   // AB store: tid = k2*8 + ijl2*2 + par -> 64B-chunked, near-coalesced
        const int k2   = tid >> 3;
        const int ijl2 = (tid >> 1) & 3;
        const int par  = tid & 1;
        AB2[(k2 << 11) + ((ij0 + ijl2) << 1) + par] = abS[ijl2][2 * k2 + par];
    }
    {   // KV store: fully linear in tid (bijection with consumer layout)
        const int pr  = tid >> 7;
        const int k6  = (tid >> 1) & 63;
        const int par = tid & 1;
        KV2[(blockIdx.x << 8) + tid] = kvS[(pr << 1) + par][k6];
    }
}

// ---------------------------------------------------------------------------
// Kernel 2: main. Block = 4 batch rows x 1024 ij, 16 waves.
// ALL per-iteration LDS broadcast reads replaced by compile-time v_readlane
// of register-resident data (X lives in xk0..3 at lane=k; W lives in wv4 of
// lanes 2p/2p+1 of the SAME wave). LDS unit (previously ~24.5k cyc/CU of
// ds_read_b128 broadcasts + per-iter lgkmcnt waits on the critical path) is
// now idle except the 20 KiB epilogue reduction.
// ---------------------------------------------------------------------------
__global__ __launch_bounds__(1024) void gmm_main_kernel(
    const float* __restrict__ X,   const float* __restrict__ Lam,
    const float* __restrict__ C0,
    const float4* __restrict__ AB4, const float4* __restrict__ KV4,
    float* __restrict__ out)
{
    __shared__ float red[16 * 64 * 5];  // [w][k][bb], stride 5: conflict-free
    __shared__ float denp[16 * 4];      // per-wave per-bb den partials

    const int tid  = threadIdx.x;
    const int lane = tid & 63;
    const int w    = tid >> 6;           // 0..15
    const int b0   = blockIdx.x << 2;

    // Per-lane X: xk_bb[lane] = X[(b0+bb)*64 + lane]. Coalesced, L1/L2-hit
    // (every block reads the same 4 rows it owns). No LDS staging, no barrier.
    const float xk0 = X[(b0 + 0) * 64 + lane];
    const float xk1 = X[(b0 + 1) * 64 + lane];
    const float xk2 = X[(b0 + 2) * 64 + lane];
    const float xk3 = X[(b0 + 3) * 64 + lane];

    // ---- Phase A: one ij per thread ----
    const int ij = tid;
    const float4* __restrict__ abp = AB4 + ij;   // stride 1024 float4 per k2
    const float c0 = C0[ij];
    const float lm = Lam[ij];

    float4 ab[8];
    #pragma unroll
    for (int g = 0; g < 8; ++g) ab[g] = abp[g << 10];

    float qa = 0.f, qb = 0.f, qc = 0.f, qd = 0.f;
    #pragma unroll
    for (int k2 = 0; k2 < 32; ++k2) {
        const float4 a = ab[k2 & 7];
        if (k2 + 8 < 32) ab[k2 & 7] = abp[(k2 + 8) << 10];
        // broadcast x values via readlane (compile-time lane): SGPR operands
        const float xe0 = rl(xk0, 2 * k2),     xo0 = rl(xk0, 2 * k2 + 1);
        const float xe1 = rl(xk1, 2 * k2),     xo1 = rl(xk1, 2 * k2 + 1);
        const float xe2 = rl(xk2, 2 * k2),     xo2 = rl(xk2, 2 * k2 + 1);
        const float xe3 = rl(xk3, 2 * k2),     xo3 = rl(xk3, 2 * k2 + 1);
        qa = fmaf(fmaf(a.x, xe0, -a.y), xe0, qa);
        qb = fmaf(fmaf(a.x, xe1, -a.y), xe1, qb);
        qc = fmaf(fmaf(a.x, xe2, -a.y), xe2, qc);
        qd = fmaf(fmaf(a.x, xe3, -a.y), xe3, qd);
        qa = fmaf(fmaf(a.z, xo0, -a.w), xo0, qa);
        qb = fmaf(fmaf(a.z, xo1, -a.w), xo1, qb);
        qc = fmaf(fmaf(a.z, xo2, -a.w), xo2, qc);
        qd = fmaf(fmaf(a.z, xo3, -a.w), xo3, qd);
    }

    #define WCALC(q) (__expf(fminf(fmaxf(-0.5f * ((q) + c0), -50.f), 50.f)) * lm)
    float4 wv4;
    wv4.x = WCALC(qa); wv4.y = WCALC(qb); wv4.z = WCALC(qc); wv4.w = WCALC(qd);
    #undef WCALC

    // ---- Phase B prologue: first 8 KV loads fly under the den reduction ----
    const int p0 = w << 5;               // first pair index of this wave
    float4 kvb[8];
    #pragma unroll
    for (int q = 0; q < 8; ++q) kvb[q] = KV4[((p0 + q) << 6) + lane];

    float d0 = wv4.x, d1 = wv4.y, d2 = wv4.z, d3 = wv4.w;
    #pragma unroll
    for (int off = 32; off >= 1; off >>= 1) {
        d0 += __shfl_xor(d0, off, 64);
        d1 += __shfl_xor(d1, off, 64);
        d2 += __shfl_xor(d2, off, 64);
        d3 += __shfl_xor(d3, off, 64);
    }
    if (lane == 0) {
        denp[w * 4 + 0] = d0; denp[w * 4 + 1] = d1;
        denp[w * 4 + 2] = d2; denp[w * 4 + 3] = d3;
    }

    // ---- Phase B: wave w, 32 ij-pairs, lane = k ----
    // W for pair p is in wv4 of lanes 2p / 2p+1 of THIS wave (ij = 64w+lane):
    // readlane, no LDS round-trip, no barrier.
    float n0 = 0.f, n1 = 0.f, n2 = 0.f, n3 = 0.f;
    #pragma unroll
    for (int p = 0; p < 32; ++p) {
        const float4 kv = kvb[p & 7];
        if (p + 8 < 32) kvb[p & 7] = KV4[((p0 + p + 8) << 6) + lane];
        const float wex = rl(wv4.x, 2 * p),     wox = rl(wv4.x, 2 * p + 1);
        const float wey = rl(wv4.y, 2 * p),     woy = rl(wv4.y, 2 * p + 1);
        const float wez = rl(wv4.z, 2 * p),     woz = rl(wv4.z, 2 * p + 1);
        const float wew = rl(wv4.w, 2 * p),     wow = rl(wv4.w, 2 * p + 1);
        float u;
        u = fmaf(kv.x, xk0, kv.y); n0 = fmaf(wex, u, n0);
        u = fmaf(kv.x, xk1, kv.y); n1 = fmaf(wey, u, n1);
        u = fmaf(kv.x, xk2, kv.y); n2 = fmaf(wez, u, n2);
        u = fmaf(kv.x, xk3, kv.y); n3 = fmaf(wew, u, n3);
        u = fmaf(kv.z, xk0, kv.w); n0 = fmaf(wox, u, n0);
        u = fmaf(kv.z, xk1, kv.w); n1 = fmaf(woy, u, n1);
        u = fmaf(kv.z, xk2, kv.w); n2 = fmaf(woz, u, n2);
        u = fmaf(kv.z, xk3, kv.w); n3 = fmaf(wow, u, n3);
    }
    {
        float* r = &red[(w * 64 + lane) * 5];
        r[0] = n0; r[1] = n1; r[2] = n2; r[3] = n3;
    }
    __syncthreads();

    // ---- Epilogue ----
    if (tid < 256) {
        const int bb = tid >> 6, k = tid & 63;   // bb wave-uniform
        float s = 0.f, d = 0.f;
        #pragma unroll
        for (int ww = 0; ww < 16; ++ww) {
            s += red[(ww * 64 + k) * 5 + bb];
            d += denp[ww * 4 + bb];
        }
        out[(b0 + bb) * 64 + k] = s / d;
    }
}

extern "C" void kernel_launch(void* const* d_in, const int* in_sizes, int n_in,
                              void* d_out, int out_size, void* d_ws, size_t ws_size,
                              hipStream_t stream) {
    const float* X   = (const float*)d_in[0];
    const float* Mu0 = (const float*)d_in[1];
    const float* Mu1 = (const float*)d_in[2];
    const float* S0  = (const float*)d_in[3];
    const float* S1  = (const float*)d_in[4];
    const float* Lam = (const float*)d_in[5];
    const float* t   = (const float*)d_in[6];
    float* out = (float*)d_out;

    char* ws = (char*)d_ws;
    float2* AB2 = (float2*)(ws);                  // 512 KiB
    float2* KV2 = (float2*)(ws + (512 << 10));    // 512 KiB
    float*  C0  = (float*)(ws + (1024 << 10));    // 4 KiB

    precomp_kernel<<<256, 256, 0, stream>>>(Mu0, Mu1, S0, S1, t, AB2, KV2, C0);
    gmm_main_kernel<<<256, 1024, 0, stream>>>(X, Lam, C0,
                                              (const float4*)AB2,
                                              (const float4*)KV2, out);
}